// Round 14
// baseline (255.435 us; speedup 1.0000x reference)
//
#include <hip/hip_runtime.h>

// GCN 2-layer forward on MI355X.
// out = Ahat @ (X W1) -> relu -> Ahat @ (H W2), Ahat = D^-1/2 (A+I) D^-1/2.
// R14: 5 dispatches (was 7).
//  1. memset bucketCur
//  2. k_fused1: blocks [0,nbA) = edge bucketing (kA); blocks [nbA,..) =
//     X@W1 gemm writing UNSCALED bf16 hs1 (no dinv dep -> runs concurrently)
//  3. kB_fill: per-bucket counting sort -> rp/col/dinv
//  4. k_aggW2: layer-1 gather (per-edge dinv fma) + relu + in-wave W2
//     product -> hs2 bf16 (h1 never materialized)
//  5. k_agg16: layer-2 gather, 8 nodes/wave -> out f32

#define NBSHIFT 9
#define BUCKET_NODES 512
#define CAP 10240
#define CHA 8192
#define TA 512
#define TB 512
#define MAXNB 160
#define EPT 16   // edges per thread in kA (CHA/TA)

__device__ __forceinline__ unsigned bfpack(float a, float b) {
  unsigned ua = __float_as_uint(a), ub = __float_as_uint(b);
  ua += 0x7fffu + ((ua >> 16) & 1u);   // RNE to bf16
  ub += 0x7fffu + ((ub >> 16) & 1u);
  return (ua >> 16) | (ub & 0xffff0000u);
}
__device__ __forceinline__ float bflo(unsigned u) { return __uint_as_float(u << 16); }
__device__ __forceinline__ float bfhi(unsigned u) { return __uint_as_float(u & 0xffff0000u); }

// ---------------- Fused: coarse bucketing || X@W1 gemm ----------------
// LDS union: kA uses 44544 B (stage/binOf/cnt/off/gpos/cursor/scanbuf);
// gemm uses 33792 B (Xs 17408 + Ws 16384).
__launch_bounds__(512)
__global__ void k_fused1(const int* __restrict__ srcp, const int* __restrict__ dstp,
                         int* __restrict__ bucketCur, int* __restrict__ bucketArr,
                         int NB, int E, int nbA,
                         const float4* __restrict__ X4, const float4* __restrict__ W4,
                         uint2* __restrict__ outb, int n) {
  __shared__ __align__(16) char smem[44544];
  int t = threadIdx.x;
  if ((int)blockIdx.x < nbA) {
    // ---- kA_bucket body ----
    int* stage = (int*)smem;                               // 8192 ints
    unsigned char* binOf = (unsigned char*)(smem + 32768); // 8192 B
    int* cnt    = (int*)(smem + 40960);
    int* off    = (int*)(smem + 41600);
    int* gpos   = (int*)(smem + 42240);
    int* cursor = (int*)(smem + 42880);
    int* scanbuf= (int*)(smem + 43520);                    // 256 ints
    int e0 = blockIdx.x * CHA;

    for (int i = t; i < NB; i += TA) cnt[i] = 0;
    __syncthreads();
    int dreg[EPT];
    #pragma unroll
    for (int j = 0; j < EPT; j++) {
      int e = e0 + t + j * TA;
      dreg[j] = (e < E) ? dstp[e] : -1;
      if (dreg[j] >= 0) atomicAdd(&cnt[dreg[j] >> NBSHIFT], 1);
    }
    __syncthreads();
    if (t < 256) scanbuf[t] = (t < NB) ? cnt[t] : 0;
    __syncthreads();
    for (int o = 1; o < 256; o <<= 1) {
      int add = (t < 256 && t >= o) ? scanbuf[t - o] : 0;
      __syncthreads();
      if (t < 256) scanbuf[t] += add;
      __syncthreads();
    }
    if (t < NB) {
      off[t] = scanbuf[t] - cnt[t];
      cursor[t] = off[t];
      gpos[t] = (cnt[t] > 0) ? atomicAdd(&bucketCur[t], cnt[t]) : 0;
    }
    __syncthreads();
    #pragma unroll
    for (int j = 0; j < EPT; j++) {
      int e = e0 + t + j * TA;
      if (dreg[j] >= 0) {
        int d = dreg[j], s = srcp[e];
        int b = d >> NBSHIFT;
        int p = atomicAdd(&cursor[b], 1);
        stage[p] = (s << NBSHIFT) | (d & (BUCKET_NODES - 1));
        binOf[p] = (unsigned char)b;
      }
    }
    __syncthreads();
    int total = scanbuf[255];
    for (int i = t; i < total; i += TA) {
      int b = binOf[i];
      int destIdx = gpos[b] + (i - off[b]);
      if (destIdx < CAP) bucketArr[b * CAP + destIdx] = stage[i];
    }
  } else {
    // ---- gemm body: hs1(bf16, UNSCALED) = X @ W1 ----
    float4* Xs = (float4*)smem;              // [64][17]
    float4* Ws = (float4*)(smem + 17408);    // [1024]
    int base = ((int)blockIdx.x - nbA) * 64;
    {
      int rr = t >> 3, q = t & 7;
      int r = base + rr;
      float4 z = make_float4(0.f, 0.f, 0.f, 0.f);
      Xs[rr * 17 + q]     = (r < n) ? X4[r * 16 + q]     : z;
      Xs[rr * 17 + q + 8] = (r < n) ? X4[r * 16 + q + 8] : z;
      Ws[t]       = W4[t];
      Ws[t + 512] = W4[t + 512];
    }
    __syncthreads();
    int tx = t & 15, tyy = t >> 4;   // tyy 0..31 -> 2 rows each
    float4 a0 = make_float4(0.f, 0.f, 0.f, 0.f), a1 = a0;
    #pragma unroll
    for (int kb = 0; kb < 16; kb++) {
      float4 x0 = Xs[(tyy * 2 + 0) * 17 + kb];
      float4 x1 = Xs[(tyy * 2 + 1) * 17 + kb];
      float4 w0 = Ws[(kb * 4 + 0) * 16 + tx];
      float4 w1 = Ws[(kb * 4 + 1) * 16 + tx];
      float4 w2 = Ws[(kb * 4 + 2) * 16 + tx];
      float4 w3 = Ws[(kb * 4 + 3) * 16 + tx];
      #define FMA4(A, XS) \
        A.x = fmaf(XS.x, w0.x, A.x); A.y = fmaf(XS.x, w0.y, A.y); \
        A.z = fmaf(XS.x, w0.z, A.z); A.w = fmaf(XS.x, w0.w, A.w); \
        A.x = fmaf(XS.y, w1.x, A.x); A.y = fmaf(XS.y, w1.y, A.y); \
        A.z = fmaf(XS.y, w1.z, A.z); A.w = fmaf(XS.y, w1.w, A.w); \
        A.x = fmaf(XS.z, w2.x, A.x); A.y = fmaf(XS.z, w2.y, A.y); \
        A.z = fmaf(XS.z, w2.z, A.z); A.w = fmaf(XS.z, w2.w, A.w); \
        A.x = fmaf(XS.w, w3.x, A.x); A.y = fmaf(XS.w, w3.y, A.y); \
        A.z = fmaf(XS.w, w3.z, A.z); A.w = fmaf(XS.w, w3.w, A.w);
      FMA4(a0, x0) FMA4(a1, x1)
      #undef FMA4
    }
    #pragma unroll
    for (int i = 0; i < 2; i++) {
      int r = base + tyy * 2 + i;
      if (r < n) {
        float4 a = i ? a1 : a0;
        uint2 pk;
        pk.x = bfpack(a.x, a.y);
        pk.y = bfpack(a.z, a.w);
        outb[r * 16 + tx] = pk;
      }
    }
  }
}

// ---------------- Pass B: per-bucket fine counting sort ----------------
__launch_bounds__(TB)
__global__ void kB_fill(const int* __restrict__ bucketArr, const int* __restrict__ bucketCur,
                        int* __restrict__ rp, float* __restrict__ dinv,
                        int* __restrict__ col, int N, int NB) {
  __shared__ int cnts[MAXNB];
  __shared__ int hist[BUCKET_NODES];
  __shared__ int cur[BUCKET_NODES];
  __shared__ int wsum[8], woff[8];
  __shared__ int s_base;
  int b = blockIdx.x;
  int t = threadIdx.x;
  int nE = min(bucketCur[b], CAP);
  int base = b * CAP;

  if (t < NB) cnts[t] = min(bucketCur[t], CAP);
  hist[t] = 0;
  __syncthreads();
  for (int i = t; i < nE; i += TB)
    atomicAdd(&hist[bucketArr[base + i] & (BUCKET_NODES - 1)], 1);
  __syncthreads();
  int myv = hist[t];
  int lane = t & 63, w = t >> 6;
  int incl = myv;
  #pragma unroll
  for (int o = 1; o < 64; o <<= 1) {
    int v = __shfl_up(incl, o);
    if (lane >= o) incl += v;
  }
  if (lane == 63) wsum[w] = incl;
  __syncthreads();
  if (t == 0) {
    int acc = 0;
    for (int i = 0; i < b; i++) acc += cnts[i];
    s_base = acc;
    int a2 = 0;
    #pragma unroll
    for (int i = 0; i < 8; i++) { woff[i] = a2; a2 += wsum[i]; }
    if (b == NB - 1) rp[N] = acc + nE;
  }
  __syncthreads();
  int gexcl = s_base + woff[w] + (incl - myv);
  cur[t] = gexcl;
  int gnode = b * BUCKET_NODES + t;
  if (gnode < N) {
    rp[gnode] = gexcl;
    dinv[gnode] = rsqrtf((float)(myv + 1));  // +1 self loop
  }
  __syncthreads();
  for (int i = t; i < nE; i += TB) {
    int v = bucketArr[base + i];
    int p = atomicAdd(&cur[v & (BUCKET_NODES - 1)], 1);
    col[p] = v >> NBSHIFT;
  }
}

// Layer-1 gather (per-edge dinv fma) + relu + fused W2 product -> hs2 bf16.
// FOUR nodes/wave (16 lanes/node, lane c owns h1 cols 4c..4c+3). 8-deep
// unrolled edge walk. Epilogue: 16x(4 shfl + 4 LDS + 4 fma) serves all
// 4 nodes of the wave simultaneously.
__launch_bounds__(256)
__global__ void k_aggW2(const uint2* __restrict__ hsb,    // [n*16] unscaled bf16
                        const int* __restrict__ rp,
                        const int* __restrict__ col,
                        const float* __restrict__ dinv,
                        const float* __restrict__ b1,
                        const float* __restrict__ W2,     // 64x16 f32
                        unsigned* __restrict__ hs2b,      // [n*8] bf16 rows
                        int n) {
  __shared__ float W2s[1024];
  for (int i = threadIdx.x; i < 1024; i += 256) W2s[i] = W2[i];
  __syncthreads();
  int lane = threadIdx.x & 63;
  int c = lane & 15;     // h1 cols 4c..4c+3
  int node = ((blockIdx.x * blockDim.x + threadIdx.x) >> 6) * 4 + (lane >> 4);
  if (node >= n) return;

  float4 b14 = ((const float4*)b1)[c];
  int s0 = rp[node], s1 = rp[node + 1];
  int dt = s1 - s0 + 1;  // [self] + col[s0..s1)
  float ax = 0.f, ay = 0.f, az = 0.f, aw = 0.f;
  int t = 0;
  int i0 = node, i1 = 0, i2 = 0, i3 = 0, i4 = 0, i5 = 0, i6 = 0, i7 = 0;
  if (1 < dt) i1 = col[s0 + 0];
  if (2 < dt) i2 = col[s0 + 1];
  if (3 < dt) i3 = col[s0 + 2];
  if (4 < dt) i4 = col[s0 + 3];
  if (5 < dt) i5 = col[s0 + 4];
  if (6 < dt) i6 = col[s0 + 5];
  if (7 < dt) i7 = col[s0 + 6];
  while (t < dt) {
    int c0 = i0, c1 = i1, c2 = i2, c3 = i3, c4 = i4, c5 = i5, c6 = i6, c7 = i7;
    bool h1_ = (t + 1) < dt, h2_ = (t + 2) < dt, h3_ = (t + 3) < dt;
    bool h4_ = (t + 4) < dt, h5_ = (t + 5) < dt, h6_ = (t + 6) < dt;
    bool h7_ = (t + 7) < dt;
    int tn = t + 8;
    if (tn + 0 < dt) i0 = col[s0 + tn - 1];
    if (tn + 1 < dt) i1 = col[s0 + tn + 0];
    if (tn + 2 < dt) i2 = col[s0 + tn + 1];
    if (tn + 3 < dt) i3 = col[s0 + tn + 2];
    if (tn + 4 < dt) i4 = col[s0 + tn + 3];
    if (tn + 5 < dt) i5 = col[s0 + tn + 4];
    if (tn + 6 < dt) i6 = col[s0 + tn + 5];
    if (tn + 7 < dt) i7 = col[s0 + tn + 6];
    float d0 = dinv[c0], d1 = dinv[c1], d2 = dinv[c2], d3 = dinv[c3];
    float d4 = dinv[c4], d5 = dinv[c5], d6 = dinv[c6], d7 = dinv[c7];
    uint2 u0 = hsb[c0 * 16 + c];
    uint2 u1 = h1_ ? hsb[c1 * 16 + c] : make_uint2(0u, 0u);
    uint2 u2 = h2_ ? hsb[c2 * 16 + c] : make_uint2(0u, 0u);
    uint2 u3 = h3_ ? hsb[c3 * 16 + c] : make_uint2(0u, 0u);
    uint2 u4 = h4_ ? hsb[c4 * 16 + c] : make_uint2(0u, 0u);
    uint2 u5 = h5_ ? hsb[c5 * 16 + c] : make_uint2(0u, 0u);
    uint2 u6 = h6_ ? hsb[c6 * 16 + c] : make_uint2(0u, 0u);
    uint2 u7 = h7_ ? hsb[c7 * 16 + c] : make_uint2(0u, 0u);
    #define ACC(U, D) \
      ax = fmaf(D, bflo(U.x), ax); ay = fmaf(D, bfhi(U.x), ay); \
      az = fmaf(D, bflo(U.y), az); aw = fmaf(D, bfhi(U.y), aw);
    ACC(u0, d0) ACC(u1, d1) ACC(u2, d2) ACC(u3, d3)
    ACC(u4, d4) ACC(u5, d5) ACC(u6, d6) ACC(u7, d7)
    #undef ACC
    t = tn;
  }
  float dv = dinv[node];
  float h0  = fmaxf(ax * dv + b14.x, 0.f);
  float h1v = fmaxf(ay * dv + b14.y, 0.f);
  float h2v = fmaxf(az * dv + b14.z, 0.f);
  float h3v = fmaxf(aw * dv + b14.w, 0.f);

  // hs2[node][c] = dv * sum_k h1[node][k] * W2[k][c]; k owner = lane gb+kq
  float val = 0.f;
  int gb = lane & 48;
  #pragma unroll
  for (int kq = 0; kq < 16; kq++) {
    int srcl = gb + kq;
    float v0 = __shfl(h0, srcl);
    float v1 = __shfl(h1v, srcl);
    float v2 = __shfl(h2v, srcl);
    float v3 = __shfl(h3v, srcl);
    val = fmaf(v0, W2s[(4 * kq + 0) * 16 + c], val);
    val = fmaf(v1, W2s[(4 * kq + 1) * 16 + c], val);
    val = fmaf(v2, W2s[(4 * kq + 2) * 16 + c], val);
    val = fmaf(v3, W2s[(4 * kq + 3) * 16 + c], val);
  }
  val *= dv;
  float vnext = __shfl_down(val, 1);
  if ((c & 1) == 0) hs2b[node * 8 + (c >> 1)] = bfpack(val, vnext);
}

// Layer-2 aggregate: EIGHT nodes per wave (8 lanes each: 2 slots x 4 lanes),
// uint2 bf16 loads (row = 32 B), 4-deep unroll. Final output f32.
__launch_bounds__(256)
__global__ void k_agg16(const uint2* __restrict__ hs2b,    // [n*4] bf16 rows
                        const int* __restrict__ rp,
                        const int* __restrict__ col,
                        const float* __restrict__ dinv,
                        const float* __restrict__ b2,
                        float4* __restrict__ out4,          // [n*4]
                        int n) {
  int lane = threadIdx.x & 63;
  int hl = lane & 7;
  int c = hl & 3;        // cols 4c..4c+3
  int sub = hl >> 2;     // slot group 0..1
  int node = ((blockIdx.x * blockDim.x + threadIdx.x) >> 6) * 8 + (lane >> 3);
  if (node >= n) return;

  int s0 = rp[node], s1 = rp[node + 1];
  int dt = s1 - s0 + 1;
  float ax = 0.f, ay = 0.f, az = 0.f, aw = 0.f;
  int t = sub;
  int i0 = 0, i1 = 0, i2 = 0, i3 = 0;
  if (t < dt)     i0 = (t == 0) ? node : col[s0 + t - 1];
  if (t + 2 < dt) i1 = col[s0 + t + 1];
  if (t + 4 < dt) i2 = col[s0 + t + 3];
  if (t + 6 < dt) i3 = col[s0 + t + 5];
  while (t < dt) {
    int c0 = i0, c1 = i1, c2 = i2, c3 = i3;
    bool h1_ = (t + 2) < dt, h2_ = (t + 4) < dt, h3_ = (t + 6) < dt;
    int tn = t + 8;
    if (tn < dt)     i0 = col[s0 + tn - 1];
    if (tn + 2 < dt) i1 = col[s0 + tn + 1];
    if (tn + 4 < dt) i2 = col[s0 + tn + 3];
    if (tn + 6 < dt) i3 = col[s0 + tn + 5];
    uint2 u0 = hs2b[c0 * 4 + c];
    uint2 u1 = h1_ ? hs2b[c1 * 4 + c] : make_uint2(0u, 0u);
    uint2 u2 = h2_ ? hs2b[c2 * 4 + c] : make_uint2(0u, 0u);
    uint2 u3 = h3_ ? hs2b[c3 * 4 + c] : make_uint2(0u, 0u);
    ax += bflo(u0.x) + bflo(u1.x) + bflo(u2.x) + bflo(u3.x);
    ay += bfhi(u0.x) + bfhi(u1.x) + bfhi(u2.x) + bfhi(u3.x);
    az += bflo(u0.y) + bflo(u1.y) + bflo(u2.y) + bflo(u3.y);
    aw += bfhi(u0.y) + bfhi(u1.y) + bfhi(u2.y) + bfhi(u3.y);
    t = tn;
  }
  ax += __shfl_xor(ax, 4);
  ay += __shfl_xor(ay, 4);
  az += __shfl_xor(az, 4);
  aw += __shfl_xor(aw, 4);
  if (sub == 0) {
    float dv = dinv[node];
    float4 b24 = ((const float4*)b2)[c];
    float4 o;
    o.x = ax * dv + b24.x;
    o.y = ay * dv + b24.y;
    o.z = az * dv + b24.z;
    o.w = aw * dv + b24.w;
    out4[node * 4 + c] = o;
  }
}

extern "C" void kernel_launch(void* const* d_in, const int* in_sizes, int n_in,
                              void* d_out, int out_size, void* d_ws, size_t ws_size,
                              hipStream_t stream) {
  const float* x  = (const float*)d_in[0];
  const int* edges = (const int*)d_in[1];
  const float* W1 = (const float*)d_in[2];
  const float* b1 = (const float*)d_in[3];
  const float* W2 = (const float*)d_in[4];
  const float* b2 = (const float*)d_in[5];
  float* out = (float*)d_out;

  const int N = in_sizes[0] / 64;
  const int E = in_sizes[1] / 2;
  const int* src = edges;
  const int* dst = edges + E;
  const int NB = (N + BUCKET_NODES - 1) >> NBSHIFT;  // 147 <= MAXNB

  auto align = [](size_t v) { return (v + 255) & ~(size_t)255; };
  char* p = (char*)d_ws;
  float* dinv       = (float*)p; p += align((size_t)N * 4);
  int*   rp         = (int*)p;   p += align((size_t)(N + 1) * 4);
  int*   bucketCur  = (int*)p;   p += align((size_t)MAXNB * 4);
  int*   col        = (int*)p;   p += align((size_t)E * 4);
  int*   bucketArr  = (int*)p;   p += align((size_t)MAXNB * CAP * 4);  // own region (concurrent with hs1 writes)
  float* hs1        = (float*)p; p += align((size_t)N * 64 * 2);       // bf16 [n][64], unscaled
  float* hs2        = (float*)p; p += align((size_t)N * 16 * 2);       // bf16 [n][16]

  const int nbA = (E + CHA - 1) / CHA;                 // 147
  const int ngemm = (N + 63) / 64;                     // 1172
  const int nbW4 = (int)((((size_t)(N + 3) / 4) * 64 + 255) / 256);  // 4 nodes/wave
  const int nbW8 = (int)((((size_t)(N + 7) / 8) * 64 + 255) / 256);  // 8 nodes/wave

  hipMemsetAsync(bucketCur, 0, (size_t)MAXNB * 4, stream);
  k_fused1<<<nbA + ngemm, 512, 0, stream>>>(src, dst, bucketCur, bucketArr,
                                            NB, E, nbA,
                                            (const float4*)x, (const float4*)W1,
                                            (uint2*)hs1, N);
  kB_fill<<<NB, TB, 0, stream>>>(bucketArr, bucketCur, rp, dinv, col, N, NB);
  k_aggW2<<<nbW4, 256, 0, stream>>>((const uint2*)hs1, rp, col, dinv,
                                    b1, W2, (unsigned*)hs2, N);
  k_agg16<<<nbW8, 256, 0, stream>>>((const uint2*)hs2, rp, col, dinv,
                                    b2, (float4*)out, N);
}

// Round 15
// 117.157 us; speedup vs baseline: 2.1803x; 2.1803x over previous
//
#include <hip/hip_runtime.h>

// GCN 2-layer forward on MI355X.
// out = Ahat @ (X W1) -> relu -> Ahat @ (H W2), Ahat = D^-1/2 (A+I) D^-1/2.
// R15 = R13 base (separate kernels; fusion of dissimilar bodies regressed
// in R14 via VGPR/LDS-max inheritance) + merged agg64+gemmB:
// k_aggW2 does layer-1 gather (scaled hs1, plain adds) + relu + in-wave
// W2 product (4 KB LDS, amortized over 4 nodes/wave) -> hs2 bf16 directly.
// 6 dispatches: memset, kA, kB, gemm64, aggW2, agg16.

#define NBSHIFT 9
#define BUCKET_NODES 512
#define CAP 10240
#define CHA 8192
#define TA 512
#define TB 512
#define MAXNB 160
#define EPT 16   // edges per thread in kA (CHA/TA)

__device__ __forceinline__ unsigned bfpack(float a, float b) {
  unsigned ua = __float_as_uint(a), ub = __float_as_uint(b);
  ua += 0x7fffu + ((ua >> 16) & 1u);   // RNE to bf16
  ub += 0x7fffu + ((ub >> 16) & 1u);
  return (ua >> 16) | (ub & 0xffff0000u);
}
__device__ __forceinline__ float bflo(unsigned u) { return __uint_as_float(u << 16); }
__device__ __forceinline__ float bfhi(unsigned u) { return __uint_as_float(u & 0xffff0000u); }

// ---------------- Pass A: coarse bucketing ----------------
__launch_bounds__(TA)
__global__ void kA_bucket(const int* __restrict__ src, const int* __restrict__ dst,
                          int* __restrict__ bucketCur, int* __restrict__ bucketArr,
                          int NB, int E) {
  __shared__ int stage[CHA];
  __shared__ unsigned char binOf[CHA];
  __shared__ int cnt[MAXNB];
  __shared__ int off[MAXNB];
  __shared__ int gpos[MAXNB];
  __shared__ int cursor[MAXNB];
  __shared__ int scanbuf[256];
  int t = threadIdx.x;
  int e0 = blockIdx.x * CHA;

  for (int i = t; i < NB; i += TA) cnt[i] = 0;
  __syncthreads();
  int dreg[EPT];
  #pragma unroll
  for (int j = 0; j < EPT; j++) {
    int e = e0 + t + j * TA;
    dreg[j] = (e < E) ? dst[e] : -1;
    if (dreg[j] >= 0) atomicAdd(&cnt[dreg[j] >> NBSHIFT], 1);
  }
  __syncthreads();
  if (t < 256) scanbuf[t] = (t < NB) ? cnt[t] : 0;
  __syncthreads();
  for (int o = 1; o < 256; o <<= 1) {
    int add = (t < 256 && t >= o) ? scanbuf[t - o] : 0;
    __syncthreads();
    if (t < 256) scanbuf[t] += add;
    __syncthreads();
  }
  if (t < NB) {
    off[t] = scanbuf[t] - cnt[t];
    cursor[t] = off[t];
    gpos[t] = (cnt[t] > 0) ? atomicAdd(&bucketCur[t], cnt[t]) : 0;
  }
  __syncthreads();
  #pragma unroll
  for (int j = 0; j < EPT; j++) {
    int e = e0 + t + j * TA;
    if (dreg[j] >= 0) {
      int d = dreg[j], s = src[e];
      int b = d >> NBSHIFT;
      int p = atomicAdd(&cursor[b], 1);
      stage[p] = (s << NBSHIFT) | (d & (BUCKET_NODES - 1));
      binOf[p] = (unsigned char)b;
    }
  }
  __syncthreads();
  int total = scanbuf[255];
  for (int i = t; i < total; i += TA) {
    int b = binOf[i];
    int destIdx = gpos[b] + (i - off[b]);
    if (destIdx < CAP) bucketArr[b * CAP + destIdx] = stage[i];
  }
}

// ---------------- Pass B: per-bucket fine counting sort ----------------
__launch_bounds__(TB)
__global__ void kB_fill(const int* __restrict__ bucketArr, const int* __restrict__ bucketCur,
                        int* __restrict__ rp, float* __restrict__ dinv,
                        int* __restrict__ col, int N, int NB) {
  __shared__ int cnts[MAXNB];
  __shared__ int hist[BUCKET_NODES];
  __shared__ int cur[BUCKET_NODES];
  __shared__ int wsum[8], woff[8];
  __shared__ int s_base;
  int b = blockIdx.x;
  int t = threadIdx.x;
  int nE = min(bucketCur[b], CAP);
  int base = b * CAP;

  if (t < NB) cnts[t] = min(bucketCur[t], CAP);
  hist[t] = 0;
  __syncthreads();
  for (int i = t; i < nE; i += TB)
    atomicAdd(&hist[bucketArr[base + i] & (BUCKET_NODES - 1)], 1);
  __syncthreads();
  int myv = hist[t];
  int lane = t & 63, w = t >> 6;
  int incl = myv;
  #pragma unroll
  for (int o = 1; o < 64; o <<= 1) {
    int v = __shfl_up(incl, o);
    if (lane >= o) incl += v;
  }
  if (lane == 63) wsum[w] = incl;
  __syncthreads();
  if (t == 0) {
    int acc = 0;
    for (int i = 0; i < b; i++) acc += cnts[i];
    s_base = acc;
    int a2 = 0;
    #pragma unroll
    for (int i = 0; i < 8; i++) { woff[i] = a2; a2 += wsum[i]; }
    if (b == NB - 1) rp[N] = acc + nE;
  }
  __syncthreads();
  int gexcl = s_base + woff[w] + (incl - myv);
  cur[t] = gexcl;
  int gnode = b * BUCKET_NODES + t;
  if (gnode < N) {
    rp[gnode] = gexcl;
    dinv[gnode] = rsqrtf((float)(myv + 1));  // +1 self loop
  }
  __syncthreads();
  for (int i = t; i < nE; i += TB) {
    int v = bucketArr[base + i];
    int p = atomicAdd(&cur[v & (BUCKET_NODES - 1)], 1);
    col[p] = v >> NBSHIFT;
  }
}

// ---------------- Dense compute ----------------
// hs1(bf16) = dinv[r] * (X @ W1). Register-tiled 64x64 block, 4x4/thread.
__launch_bounds__(256)
__global__ void k_gemm64(const float4* __restrict__ X4, const float4* __restrict__ W4,
                         const float* __restrict__ dinv, uint2* __restrict__ outb,
                         int n) {
  __shared__ float4 Xs[64 * 17];
  __shared__ float4 Ws[64 * 16];
  int t = threadIdx.x;
  int base = blockIdx.x * 64;
  {
    int rr = t >> 2, q = t & 3;
    int r = base + rr;
    #pragma unroll
    for (int c = 0; c < 4; c++) {
      float4 v = make_float4(0.f, 0.f, 0.f, 0.f);
      if (r < n) v = X4[r * 16 + q * 4 + c];
      Xs[rr * 17 + q * 4 + c] = v;
      Ws[t + 256 * c] = W4[t + 256 * c];
    }
  }
  __syncthreads();

  int tx = t & 15, ty = t >> 4;
  float4 a0 = make_float4(0.f, 0.f, 0.f, 0.f), a1 = a0, a2 = a0, a3 = a0;
  #pragma unroll
  for (int kb = 0; kb < 16; kb++) {
    float4 x0 = Xs[(ty * 4 + 0) * 17 + kb];
    float4 x1 = Xs[(ty * 4 + 1) * 17 + kb];
    float4 x2 = Xs[(ty * 4 + 2) * 17 + kb];
    float4 x3 = Xs[(ty * 4 + 3) * 17 + kb];
    float4 w0 = Ws[(kb * 4 + 0) * 16 + tx];
    float4 w1 = Ws[(kb * 4 + 1) * 16 + tx];
    float4 w2 = Ws[(kb * 4 + 2) * 16 + tx];
    float4 w3 = Ws[(kb * 4 + 3) * 16 + tx];
    #define FMA4(A, XS) \
      A.x = fmaf(XS.x, w0.x, A.x); A.y = fmaf(XS.x, w0.y, A.y); \
      A.z = fmaf(XS.x, w0.z, A.z); A.w = fmaf(XS.x, w0.w, A.w); \
      A.x = fmaf(XS.y, w1.x, A.x); A.y = fmaf(XS.y, w1.y, A.y); \
      A.z = fmaf(XS.y, w1.z, A.z); A.w = fmaf(XS.y, w1.w, A.w); \
      A.x = fmaf(XS.z, w2.x, A.x); A.y = fmaf(XS.z, w2.y, A.y); \
      A.z = fmaf(XS.z, w2.z, A.z); A.w = fmaf(XS.z, w2.w, A.w); \
      A.x = fmaf(XS.w, w3.x, A.x); A.y = fmaf(XS.w, w3.y, A.y); \
      A.z = fmaf(XS.w, w3.z, A.z); A.w = fmaf(XS.w, w3.w, A.w);
    FMA4(a0, x0) FMA4(a1, x1) FMA4(a2, x2) FMA4(a3, x3)
    #undef FMA4
  }
  #pragma unroll
  for (int i = 0; i < 4; i++) {
    int r = base + ty * 4 + i;
    if (r < n) {
      float s = dinv[r];
      float4 a = (i == 0) ? a0 : (i == 1) ? a1 : (i == 2) ? a2 : a3;
      uint2 pk;
      pk.x = bfpack(a.x * s, a.y * s);
      pk.y = bfpack(a.z * s, a.w * s);
      outb[r * 16 + tx] = pk;   // row stride 16 uint2 = 128 B
    }
  }
}

// Layer-1 aggregate + relu + fused W2 -> hs2 bf16. FOUR nodes per wave,
// 16 lanes/node (lane c owns h1 cols 4c..4c+3; zero-reduce gather).
// 8-deep unrolled edge walk. W2 epilogue: 16x(4 shfl + 4 LDS + 4 fma)
// serves all 4 nodes of the wave simultaneously (verified in R14).
__launch_bounds__(256)
__global__ void k_aggW2(const uint2* __restrict__ hsb,    // [n*16] scaled bf16
                        const int* __restrict__ rp,
                        const int* __restrict__ col,
                        const float* __restrict__ dinv,
                        const float* __restrict__ b1,
                        const float* __restrict__ W2,     // 64x16 f32
                        unsigned* __restrict__ hs2b,      // [n*8] bf16 rows
                        int n) {
  __shared__ float W2s[1024];
  for (int i = threadIdx.x; i < 1024; i += 256) W2s[i] = W2[i];
  __syncthreads();
  int lane = threadIdx.x & 63;
  int c = lane & 15;     // h1 cols 4c..4c+3
  int node = ((blockIdx.x * blockDim.x + threadIdx.x) >> 6) * 4 + (lane >> 4);
  if (node >= n) return;

  float4 b14 = ((const float4*)b1)[c];
  int s0 = rp[node], s1 = rp[node + 1];
  int dt = s1 - s0 + 1;  // [self] + col[s0..s1)
  float ax = 0.f, ay = 0.f, az = 0.f, aw = 0.f;
  int t = 0;
  int i0 = node, i1 = 0, i2 = 0, i3 = 0, i4 = 0, i5 = 0, i6 = 0, i7 = 0;
  if (1 < dt) i1 = col[s0 + 0];
  if (2 < dt) i2 = col[s0 + 1];
  if (3 < dt) i3 = col[s0 + 2];
  if (4 < dt) i4 = col[s0 + 3];
  if (5 < dt) i5 = col[s0 + 4];
  if (6 < dt) i6 = col[s0 + 5];
  if (7 < dt) i7 = col[s0 + 6];
  while (t < dt) {
    int c0 = i0, c1 = i1, c2 = i2, c3 = i3, c4 = i4, c5 = i5, c6 = i6, c7 = i7;
    bool h1_ = (t + 1) < dt, h2_ = (t + 2) < dt, h3_ = (t + 3) < dt;
    bool h4_ = (t + 4) < dt, h5_ = (t + 5) < dt, h6_ = (t + 6) < dt;
    bool h7_ = (t + 7) < dt;
    int tn = t + 8;
    if (tn + 0 < dt) i0 = col[s0 + tn - 1];
    if (tn + 1 < dt) i1 = col[s0 + tn + 0];
    if (tn + 2 < dt) i2 = col[s0 + tn + 1];
    if (tn + 3 < dt) i3 = col[s0 + tn + 2];
    if (tn + 4 < dt) i4 = col[s0 + tn + 3];
    if (tn + 5 < dt) i5 = col[s0 + tn + 4];
    if (tn + 6 < dt) i6 = col[s0 + tn + 5];
    if (tn + 7 < dt) i7 = col[s0 + tn + 6];
    uint2 u0 = hsb[c0 * 16 + c];
    uint2 u1 = h1_ ? hsb[c1 * 16 + c] : make_uint2(0u, 0u);
    uint2 u2 = h2_ ? hsb[c2 * 16 + c] : make_uint2(0u, 0u);
    uint2 u3 = h3_ ? hsb[c3 * 16 + c] : make_uint2(0u, 0u);
    uint2 u4 = h4_ ? hsb[c4 * 16 + c] : make_uint2(0u, 0u);
    uint2 u5 = h5_ ? hsb[c5 * 16 + c] : make_uint2(0u, 0u);
    uint2 u6 = h6_ ? hsb[c6 * 16 + c] : make_uint2(0u, 0u);
    uint2 u7 = h7_ ? hsb[c7 * 16 + c] : make_uint2(0u, 0u);
    #define ACC(U) \
      ax += bflo(U.x); ay += bfhi(U.x); az += bflo(U.y); aw += bfhi(U.y);
    ACC(u0) ACC(u1) ACC(u2) ACC(u3) ACC(u4) ACC(u5) ACC(u6) ACC(u7)
    #undef ACC
    t = tn;
  }
  float dv = dinv[node];
  float h0  = fmaxf(ax * dv + b14.x, 0.f);
  float h1v = fmaxf(ay * dv + b14.y, 0.f);
  float h2v = fmaxf(az * dv + b14.z, 0.f);
  float h3v = fmaxf(aw * dv + b14.w, 0.f);

  // hs2[node][c] = dv * sum_k h1[node][k] * W2[k][c]; k owner = lane gb+kq
  float val = 0.f;
  int gb = lane & 48;
  #pragma unroll
  for (int kq = 0; kq < 16; kq++) {
    int srcl = gb + kq;
    float v0 = __shfl(h0, srcl);
    float v1 = __shfl(h1v, srcl);
    float v2 = __shfl(h2v, srcl);
    float v3 = __shfl(h3v, srcl);
    val = fmaf(v0, W2s[(4 * kq + 0) * 16 + c], val);
    val = fmaf(v1, W2s[(4 * kq + 1) * 16 + c], val);
    val = fmaf(v2, W2s[(4 * kq + 2) * 16 + c], val);
    val = fmaf(v3, W2s[(4 * kq + 3) * 16 + c], val);
  }
  val *= dv;
  float vnext = __shfl_down(val, 1);
  if ((c & 1) == 0) hs2b[node * 8 + (c >> 1)] = bfpack(val, vnext);
}

// Layer-2 aggregate: EIGHT nodes per wave (8 lanes each: 2 slots x 4 lanes),
// uint2 bf16 loads (row = 32 B), 4-deep unroll. Final output f32.
__launch_bounds__(256)
__global__ void k_agg16(const uint2* __restrict__ hs2b,    // [n*4] bf16 rows
                        const int* __restrict__ rp,
                        const int* __restrict__ col,
                        const float* __restrict__ dinv,
                        const float* __restrict__ b2,
                        float4* __restrict__ out4,          // [n*4]
                        int n) {
  int lane = threadIdx.x & 63;
  int hl = lane & 7;
  int c = hl & 3;        // cols 4c..4c+3
  int sub = hl >> 2;     // slot group 0..1
  int node = ((blockIdx.x * blockDim.x + threadIdx.x) >> 6) * 8 + (lane >> 3);
  if (node >= n) return;

  int s0 = rp[node], s1 = rp[node + 1];
  int dt = s1 - s0 + 1;
  float ax = 0.f, ay = 0.f, az = 0.f, aw = 0.f;
  int t = sub;
  int i0 = 0, i1 = 0, i2 = 0, i3 = 0;
  if (t < dt)     i0 = (t == 0) ? node : col[s0 + t - 1];
  if (t + 2 < dt) i1 = col[s0 + t + 1];
  if (t + 4 < dt) i2 = col[s0 + t + 3];
  if (t + 6 < dt) i3 = col[s0 + t + 5];
  while (t < dt) {
    int c0 = i0, c1 = i1, c2 = i2, c3 = i3;
    bool h1_ = (t + 2) < dt, h2_ = (t + 4) < dt, h3_ = (t + 6) < dt;
    int tn = t + 8;
    if (tn < dt)     i0 = col[s0 + tn - 1];
    if (tn + 2 < dt) i1 = col[s0 + tn + 1];
    if (tn + 4 < dt) i2 = col[s0 + tn + 3];
    if (tn + 6 < dt) i3 = col[s0 + tn + 5];
    uint2 u0 = hs2b[c0 * 4 + c];
    uint2 u1 = h1_ ? hs2b[c1 * 4 + c] : make_uint2(0u, 0u);
    uint2 u2 = h2_ ? hs2b[c2 * 4 + c] : make_uint2(0u, 0u);
    uint2 u3 = h3_ ? hs2b[c3 * 4 + c] : make_uint2(0u, 0u);
    ax += bflo(u0.x) + bflo(u1.x) + bflo(u2.x) + bflo(u3.x);
    ay += bfhi(u0.x) + bfhi(u1.x) + bfhi(u2.x) + bfhi(u3.x);
    az += bflo(u0.y) + bflo(u1.y) + bflo(u2.y) + bflo(u3.y);
    aw += bfhi(u0.y) + bfhi(u1.y) + bfhi(u2.y) + bfhi(u3.y);
    t = tn;
  }
  ax += __shfl_xor(ax, 4);
  ay += __shfl_xor(ay, 4);
  az += __shfl_xor(az, 4);
  aw += __shfl_xor(aw, 4);
  if (sub == 0) {
    float dv = dinv[node];
    float4 b24 = ((const float4*)b2)[c];
    float4 o;
    o.x = ax * dv + b24.x;
    o.y = ay * dv + b24.y;
    o.z = az * dv + b24.z;
    o.w = aw * dv + b24.w;
    out4[node * 4 + c] = o;
  }
}

extern "C" void kernel_launch(void* const* d_in, const int* in_sizes, int n_in,
                              void* d_out, int out_size, void* d_ws, size_t ws_size,
                              hipStream_t stream) {
  const float* x  = (const float*)d_in[0];
  const int* edges = (const int*)d_in[1];
  const float* W1 = (const float*)d_in[2];
  const float* b1 = (const float*)d_in[3];
  const float* W2 = (const float*)d_in[4];
  const float* b2 = (const float*)d_in[5];
  float* out = (float*)d_out;

  const int N = in_sizes[0] / 64;
  const int E = in_sizes[1] / 2;
  const int* src = edges;
  const int* dst = edges + E;
  const int NB = (N + BUCKET_NODES - 1) >> NBSHIFT;  // 147 <= MAXNB

  auto align = [](size_t v) { return (v + 255) & ~(size_t)255; };
  char* p = (char*)d_ws;
  float* dinv       = (float*)p; p += align((size_t)N * 4);
  int*   rp         = (int*)p;   p += align((size_t)(N + 1) * 4);
  int*   bucketCur  = (int*)p;   p += align((size_t)MAXNB * 4);
  int*   col        = (int*)p;   p += align((size_t)E * 4);
  float* hs1        = (float*)p; p += align((size_t)N * 64 * 4);  // bf16 rows use half
  float* hs2        = (float*)p; p += align((size_t)N * 16 * 2);  // bf16 [n][16]
  // bucketArr (~6 MB) aliases hs1 region: pass A/B finish before k_gemm64
  // overwrites it (serial stream).
  int* bucketArr = (int*)hs1;

  const int nbA = (E + CHA - 1) / CHA;
  const int nbW4 = (int)((((size_t)(N + 3) / 4) * 64 + 255) / 256);  // 4 nodes/wave
  const int nbW8 = (int)((((size_t)(N + 7) / 8) * 64 + 255) / 256);  // 8 nodes/wave

  hipMemsetAsync(bucketCur, 0, (size_t)MAXNB * 4, stream);
  kA_bucket<<<nbA, TA, 0, stream>>>(src, dst, bucketCur, bucketArr, NB, E);
  kB_fill  <<<NB, TB, 0, stream>>>(bucketArr, bucketCur, rp, dinv, col, N, NB);

  k_gemm64<<<(N + 63) / 64, 256, 0, stream>>>((const float4*)x, (const float4*)W1,
                                              dinv, (uint2*)hs1, N);
  k_aggW2 <<<nbW4, 256, 0, stream>>>((const uint2*)hs1, rp, col, dinv,
                                     b1, W2, (unsigned*)hs2, N);
  k_agg16 <<<nbW8, 256, 0, stream>>>((const uint2*)hs2, rp, col, dinv,
                                     b2, (float4*)out, N);
}